// Round 10
// baseline (475.656 us; speedup 1.0000x reference)
//
#include <hip/hip_runtime.h>
#include <hip/hip_bf16.h>

typedef __bf16 bf16;
typedef __bf16 bf16x8 __attribute__((ext_vector_type(8)));
typedef __bf16 bf16x4 __attribute__((ext_vector_type(4)));
typedef float f32x4 __attribute__((ext_vector_type(4)));

#define NBIG 7168
#define KBIG 2048

__device__ __forceinline__ float sigmoid_f(float x) { return 1.0f / (1.0f + __expf(-x)); }
__device__ __forceinline__ float tanh_f(float x) { return 1.0f - 2.0f / (__expf(2.0f * x) + 1.0f); }

__device__ __forceinline__ void gload_lds16(const bf16* g, bf16* lds) {
  __builtin_amdgcn_global_load_lds(
      (const __attribute__((address_space(1))) unsigned int*)g,
      (__attribute__((address_space(3))) unsigned int*)lds,
      16, 0, 0);
}

// ---------------- prep kernels ----------------

__global__ __launch_bounds__(256) void build_A(const float* __restrict__ x,
                                               const float* __restrict__ h,
                                               bf16* __restrict__ A) {
  const int i4 = blockIdx.x * 256 + threadIdx.x;
  const int o = i4 * 4;
  const int m = o >> 11;
  const int c = o & 2047;
  const float4 v = (c < 1024) ? *(const float4*)&x[(size_t)m * 1024 + c]
                              : *(const float4*)&h[(size_t)m * 1024 + (c - 1024)];
  bf16x4 b;
  b[0] = (bf16)v.x; b[1] = (bf16)v.y; b[2] = (bf16)v.z; b[3] = (bf16)v.w;
  *(bf16x4*)&A[(size_t)o] = b;
}

__global__ __launch_bounds__(256) void build_WG(
    const float* __restrict__ Wi, const float* __restrict__ Wf, const float* __restrict__ Wo,
    const float* __restrict__ Wc, const float* __restrict__ Ws,
    const float* __restrict__ Ui, const float* __restrict__ Uf, const float* __restrict__ Uo,
    const float* __restrict__ Uc, const float* __restrict__ Us,
    const float* __restrict__ a1w, const float* __restrict__ r1w, bf16* __restrict__ WG) {
  const int i4 = blockIdx.x * 256 + threadIdx.x;
  const int o = i4 * 4;
  const int n = o >> 11;
  const int c = o & 2047;
  const int g = n >> 10;
  const int r = n & 1023;
  float4 v;
  if (g < 5) {
    const float* Wp = g == 0 ? Wi : g == 1 ? Wf : g == 2 ? Wo : g == 3 ? Wc : Ws;
    const float* Up = g == 0 ? Ui : g == 1 ? Uf : g == 2 ? Uo : g == 3 ? Uc : Us;
    v = (c < 1024) ? *(const float4*)&Wp[(size_t)r * 1024 + c]
                   : *(const float4*)&Up[(size_t)r * 1024 + (c - 1024)];
  } else if (g == 5) {
    v = *(const float4*)&a1w[(size_t)r * 2048 + c];
  } else {
    if (c < 1024) return;  // never read: r1 slab K-tiles 0..15 skipped in gemm256
    v = *(const float4*)&r1w[(size_t)r * 1024 + (c - 1024)];
  }
  bf16x4 b;
  b[0] = (bf16)v.x; b[1] = (bf16)v.y; b[2] = (bf16)v.z; b[3] = (bf16)v.w;
  *(bf16x4*)&WG[(size_t)o] = b;
}

__global__ __launch_bounds__(256) void build_bias(
    const float* __restrict__ Wib, const float* __restrict__ Wfb, const float* __restrict__ Wob,
    const float* __restrict__ Wcb, const float* __restrict__ Wsb,
    const float* __restrict__ Uib, const float* __restrict__ Ufb, const float* __restrict__ Uob,
    const float* __restrict__ Ucb, const float* __restrict__ Usb,
    const float* __restrict__ a1b, const float* __restrict__ r1b, float* __restrict__ bias) {
  const int n = blockIdx.x * 256 + threadIdx.x;
  if (n >= NBIG) return;
  const int g = n >> 10, r = n & 1023;
  float v;
  if (g < 5) {
    const float* Wb = g == 0 ? Wib : g == 1 ? Wfb : g == 2 ? Wob : g == 3 ? Wcb : Wsb;
    const float* Ub = g == 0 ? Uib : g == 1 ? Ufb : g == 2 ? Uob : g == 3 ? Ucb : Usb;
    v = Wb[r] + Ub[r];
  } else if (g == 5) v = a1b[r];
  else v = r1b[r];
  bias[n] = v;
}

// both r2_w and r3_w -> bf16 in one launch
__global__ __launch_bounds__(256) void f2b2(const float* __restrict__ s0,
                                            const float* __restrict__ s1,
                                            bf16* __restrict__ d0, bf16* __restrict__ d1) {
  const int i = blockIdx.x * 256 + threadIdx.x;  // < 2*262144
  const int which = i >> 18;
  const int j = i & 262143;
  const float* s = which ? s1 : s0;
  bf16* d = which ? d1 : d0;
  const float4 v = *(const float4*)&s[(size_t)j * 4];
  bf16x4 b;
  b[0] = (bf16)v.x; b[1] = (bf16)v.y; b[2] = (bf16)v.z; b[3] = (bf16)v.w;
  *(bf16x4*)&d[(size_t)j * 4] = b;
}

// ---------------- 256x256 GEMM, BK=64, 8 waves (2Mx4N, 128x64/wave) -------------
// 512 threads; m201 wave geometry (reduces redundant LDS frag reads 25%: A-half
// read by 4 waves, B-quarter by 2), r7-proven coarse schedule: two K-subphases
// {12 ds_read -> 32 MFMA}, then BAR -> STGT (8 gloads) -> counted VM8 -> BAR.
// acc[8][4]=128 AGPR + 48 frag VGPRs ~= 190 regs -> 2 waves/SIMD, no spill.
// Swizzle (128-B rows): phys 16B slot = logical ^ (fr&7) on ds_read; inverse on
// global staging source (linear gload_lds dest). kt0 K-skip for the r1 slab.
// act_mode 0: per-col regions (n>>10: 0,1,2,4=sigmoid, 3=tanh, 5,6=relu); 1: relu; 2: none.

#define BAR __builtin_amdgcn_s_barrier()
#define VM8 asm volatile("s_waitcnt vmcnt(8)" ::: "memory")
#define VM4 asm volatile("s_waitcnt vmcnt(4)" ::: "memory")
#define VM0 asm volatile("s_waitcnt vmcnt(0)" ::: "memory")
#define PRIO1 __builtin_amdgcn_s_setprio(1)
#define PRIO0 __builtin_amdgcn_s_setprio(0)

__global__ __launch_bounds__(512, 2) void gemm256(
    const bf16* __restrict__ A, int lda,
    const bf16* __restrict__ W, int ldw, int K,
    const float* __restrict__ bias,
    bf16* __restrict__ C, int ldc, int act_mode, int mtiles) {
  __shared__ __align__(16) bf16 sA[2][256 * 64];
  __shared__ __align__(16) bf16 sB[2][256 * 64];

  const int tid = threadIdx.x;
  const int lane = tid & 63;
  const int wv = tid >> 6;   // 0..7
  const int wr = wv >> 2;    // 0..1 -> 128-row half
  const int wc = wv & 3;     // 0..3 -> 64-col quarter

  int bmi, bni;
  if (gridDim.x == 896) {
    const int xcd = blockIdx.x & 7;
    const int idx = blockIdx.x >> 3;
    bmi = (xcd >> 2) * 16 + idx / 7;
    bni = (xcd & 3) * 7 + idx % 7;
  } else {
    bmi = blockIdx.x % mtiles;
    bni = blockIdx.x / mtiles;
  }
  const int bm = bmi * 256;
  const int bn = bni * 256;

  // K-skip: r1 slab (bn >= 6144) has zero weights for K < 1024
  const int kt0 = (act_mode == 0 && bni >= 24) ? 16 : 0;

  const int srow = tid >> 3;
  const int scol = ((tid & 7) ^ (srow & 7)) * 8;
  const bf16* pA = A + (size_t)(bm + srow) * lda + scol + (size_t)kt0 * 64;
  const bf16* pB = W + (size_t)(bn + srow) * ldw + scol + (size_t)kt0 * 64;

  const int fr = lane & 15;
  const int lg = lane >> 4;
  const int off0 = (lg * 16) ^ ((fr & 7) << 4);

  const int NT = (K >> 6) - kt0;  // BK=64

  f32x4 acc[8][4] = {};
  bf16x8 ar[8], br[4];

#define STGT(bb, tt)                                                        \
  do {                                                                      \
    const bf16* gA = pA + (size_t)(tt) * 64;                                \
    bf16* lA = &sA[bb][(wv * 8) * 64];                                      \
    gload_lds16(gA, lA);                                                    \
    gload_lds16(gA + (size_t)64 * lda, lA + 64 * 64);                       \
    gload_lds16(gA + (size_t)128 * lda, lA + 128 * 64);                     \
    gload_lds16(gA + (size_t)192 * lda, lA + 192 * 64);                     \
    const bf16* gB = pB + (size_t)(tt) * 64;                                \
    bf16* lB = &sB[bb][(wv * 8) * 64];                                      \
    gload_lds16(gB, lB);                                                    \
    gload_lds16(gB + (size_t)64 * ldw, lB + 64 * 64);                       \
    gload_lds16(gB + (size_t)128 * ldw, lB + 128 * 64);                     \
    gload_lds16(gB + (size_t)192 * ldw, lB + 192 * 64);                     \
  } while (0)
#define LDF(bb, kkc)                                                             \
  do {                                                                           \
    _Pragma("unroll") for (int mi = 0; mi < 8; ++mi)                             \
        ar[mi] = *(const bf16x8*)((const char*)&sA[bb][0] +                      \
            (wr * 128 + mi * 16 + fr) * 128 + (off0 ^ ((kkc) << 6)));            \
    _Pragma("unroll") for (int nj = 0; nj < 4; ++nj)                             \
        br[nj] = *(const bf16x8*)((const char*)&sB[bb][0] +                      \
            (wc * 64 + nj * 16 + fr) * 128 + (off0 ^ ((kkc) << 6)));             \
  } while (0)
#define MM()                                                                     \
  do {                                                                           \
    _Pragma("unroll") for (int mi = 0; mi < 8; ++mi)                             \
    _Pragma("unroll") for (int nj = 0; nj < 4; ++nj)                             \
      acc[mi][nj] = __builtin_amdgcn_mfma_f32_16x16x32_bf16(                     \
          ar[mi], br[nj], acc[mi][nj], 0, 0, 0);                                 \
  } while (0)

  STGT(0, 0);
  STGT(1, 1);
  VM8; BAR;

  for (int t = 0; t + 2 < NT; ++t) {
    const int b = t & 1;
    LDF(b, 0);
    PRIO1; MM(); PRIO0;
    LDF(b, 1);
    PRIO1; MM(); PRIO0;
    BAR;
    STGT(b, t + 2);
    VM8;
    BAR;
  }

  {
    const int b = NT & 1;
    LDF(b, 0); PRIO1; MM(); PRIO0;
    LDF(b, 1); PRIO1; MM(); PRIO0;
    BAR; VM0; BAR;
    LDF(b ^ 1, 0); PRIO1; MM(); PRIO0;
    LDF(b ^ 1, 1); PRIO1; MM(); PRIO0;
  }

  const int rbase = lg * 4;
#pragma unroll
  for (int j = 0; j < 4; ++j) {
    const int n = bn + wc * 64 + j * 16 + fr;
    const float bv = bias[n];
    const int g = (act_mode == 0) ? (n >> 10) : (act_mode == 1 ? 100 : 101);
#pragma unroll
    for (int mi = 0; mi < 8; ++mi) {
      const size_t mrow = (size_t)(bm + wr * 128 + mi * 16 + rbase);
#pragma unroll
      for (int r = 0; r < 4; ++r) {
        float v = acc[mi][j][r] + bv;
        if (g == 3) v = tanh_f(v);
        else if (g < 5) v = sigmoid_f(v);
        else if (g < 7 || g == 100) v = fmaxf(v, 0.0f);
        C[(mrow + r) * (size_t)ldc + n] = (bf16)v;
      }
    }
  }
#undef STGT
#undef LDF
#undef MM
}

// ---------------- 128x128 GEMM, BK=32, 3-buf, 1 barrier/tile (residual chain) ----
__global__ __launch_bounds__(256, 3) void gemm128(
    const bf16* __restrict__ A, int lda,
    const bf16* __restrict__ W, int ldw, int K,
    const float* __restrict__ bias,
    bf16* __restrict__ C, int ldc, int act_mode, int mtiles) {
  __shared__ __align__(16) bf16 sA[3][128 * 32];
  __shared__ __align__(16) bf16 sB[3][128 * 32];

  const int tid = threadIdx.x;
  const int lane = tid & 63;
  const int wv = tid >> 6;
  const int wr = wv >> 1, wc = wv & 1;

  const int bmi = blockIdx.x % mtiles;
  const int bni = blockIdx.x / mtiles;
  const int bm = bmi * 128;
  const int bn = bni * 128;

  const int srow = tid >> 2;
  const int scol = ((tid & 3) ^ ((tid >> 3) & 3)) * 8;
  const bf16* pA = A + (size_t)(bm + srow) * lda + scol;
  const bf16* pB = W + (size_t)(bn + srow) * ldw + scol;

  const int fr = lane & 15;
  const int lg = lane >> 4;
  const int sw16 = (lg ^ ((fr >> 1) & 3)) << 4;

  const int NT = K >> 5;

  f32x4 acc[4][4] = {};
  bf16x8 ar[4], br[4];

#define STGT(bb, tt)                                                \
  do {                                                              \
    const bf16* gA = pA + (size_t)(tt) * 32;                        \
    bf16* lA = &sA[bb][(wv * 16) * 32];                             \
    gload_lds16(gA, lA);                                            \
    gload_lds16(gA + (size_t)64 * lda, lA + 64 * 32);               \
    const bf16* gB = pB + (size_t)(tt) * 32;                        \
    bf16* lB = &sB[bb][(wv * 16) * 32];                             \
    gload_lds16(gB, lB);                                            \
    gload_lds16(gB + (size_t)64 * ldw, lB + 64 * 32);               \
  } while (0)
#define LDF(bb)                                                                  \
  do {                                                                           \
    _Pragma("unroll") for (int mi = 0; mi < 4; ++mi)                             \
        ar[mi] = *(const bf16x8*)((const char*)&sA[bb][0] +                      \
            (wr * 64 + mi * 16 + fr) * 64 + sw16);                               \
    _Pragma("unroll") for (int nj = 0; nj < 4; ++nj)                             \
        br[nj] = *(const bf16x8*)((const char*)&sB[bb][0] +                      \
            (wc * 64 + nj * 16 + fr) * 64 + sw16);                               \
  } while (0)
#define MM()                                                                     \
  do {                                                                           \
    _Pragma("unroll") for (int mi = 0; mi < 4; ++mi)                             \
    _Pragma("unroll") for (int nj = 0; nj < 4; ++nj)                             \
      acc[mi][nj] = __builtin_amdgcn_mfma_f32_16x16x32_bf16(                     \
          ar[mi], br[nj], acc[mi][nj], 0, 0, 0);                                 \
  } while (0)

  STGT(0, 0);
  STGT(1, 1);
  VM4; BAR;

  int bld = 0, bst = 2;
  for (int t = 0; t + 2 < NT; ++t) {
    STGT(bst, t + 2);
    LDF(bld);
    PRIO1; MM(); PRIO0;
    VM4;
    BAR;
    bld = bld == 2 ? 0 : bld + 1;
    bst = bst == 2 ? 0 : bst + 1;
  }

  LDF(bld);
  PRIO1; MM(); PRIO0;
  VM0; BAR;
  bld = bld == 2 ? 0 : bld + 1;
  LDF(bld);
  PRIO1; MM(); PRIO0;

  const int rbase = lg * 4;
#pragma unroll
  for (int j = 0; j < 4; ++j) {
    const int n = bn + wc * 64 + j * 16 + fr;
    const float bv = bias[n];
    const int g = (act_mode == 0) ? (n >> 10) : (act_mode == 1 ? 100 : 101);
#pragma unroll
    for (int mi = 0; mi < 4; ++mi) {
      const size_t mrow = (size_t)(bm + wr * 64 + mi * 16 + rbase);
#pragma unroll
      for (int r = 0; r < 4; ++r) {
        float v = acc[mi][j][r] + bv;
        if (g == 3) v = tanh_f(v);
        else if (g < 5) v = sigmoid_f(v);
        else if (g < 7 || g == 100) v = fmaxf(v, 0.0f);
        C[(mrow + r) * (size_t)ldc + n] = (bf16)v;
      }
    }
  }
#undef STGT
#undef LDF
#undef MM
}

// ---------------- alpha head ----------------
__global__ __launch_bounds__(256) void alpha_k(const bf16* __restrict__ G,
                                               const float* __restrict__ a2w,
                                               const float* __restrict__ a2b,
                                               float* __restrict__ alpha) {
  const int m = blockIdx.x * 4 + (threadIdx.x >> 6);
  const int lane = threadIdx.x & 63;
  const bf16* row = G + (size_t)m * NBIG + 5120 + lane * 16;
  const bf16x8 v0 = *(const bf16x8*)row;
  const bf16x8 v1 = *(const bf16x8*)(row + 8);
  const float* w = a2w + lane * 16;
  float s = 0.f;
#pragma unroll
  for (int e = 0; e < 8; ++e) s += (float)v0[e] * w[e] + (float)v1[e] * w[8 + e];
#pragma unroll
  for (int off = 32; off > 0; off >>= 1) s += __shfl_down(s, off, 64);
  if (lane == 0) alpha[m] = sigmoid_f(s + a2b[0]);
}

// ---------------- final elementwise ----------------
__global__ __launch_bounds__(256) void final_k(const bf16* __restrict__ G,
                                               const bf16* __restrict__ R3,
                                               const float* __restrict__ c_prev,
                                               const float* __restrict__ alpha,
                                               float* __restrict__ out) {
  const int idx = blockIdx.x * 256 + threadIdx.x;
  const int o = idx * 8;
  const int m = o >> 10;
  const int c = o & 1023;
  const size_t gb = (size_t)m * NBIG;
  const bf16x8 iv = *(const bf16x8*)&G[gb + c];
  const bf16x8 fv = *(const bf16x8*)&G[gb + 1024 + c];
  const bf16x8 ov = *(const bf16x8*)&G[gb + 2048 + c];
  const bf16x8 cv = *(const bf16x8*)&G[gb + 3072 + c];
  const bf16x8 sv = *(const bf16x8*)&G[gb + 4096 + c];
  const bf16x8 rv = *(const bf16x8*)&R3[(size_t)m * 1024 + c];
  const float al = alpha[m];
  const float* cp = &c_prev[(size_t)m * 1024 + c];
  float hbuf[8], cbuf[8];
#pragma unroll
  for (int e = 0; e < 8; ++e) {
    const float ct = (float)fv[e] * cp[e] + (float)iv[e] * (float)cv[e] * (float)sv[e] * al
                     + (float)rv[e];
    cbuf[e] = ct;
    hbuf[e] = (float)ov[e] * tanh_f(ct);
  }
  float* oh = out + (size_t)m * 1024 + c;
  float* oc = out + (size_t)8192 * 1024 + (size_t)m * 1024 + c;
#pragma unroll
  for (int e = 0; e < 8; ++e) { oh[e] = hbuf[e]; oc[e] = cbuf[e]; }
}

// ---------------- launch ----------------
extern "C" void kernel_launch(void* const* d_in, const int* in_sizes, int n_in,
                              void* d_out, int out_size, void* d_ws, size_t ws_size,
                              hipStream_t stream) {
  const float* x      = (const float*)d_in[0];
  const float* h_prev = (const float*)d_in[1];
  const float* c_prev = (const float*)d_in[2];
  const float* Wi_w = (const float*)d_in[3];  const float* Wi_b = (const float*)d_in[4];
  const float* Wf_w = (const float*)d_in[5];  const float* Wf_b = (const float*)d_in[6];
  const float* Wo_w = (const float*)d_in[7];  const float* Wo_b = (const float*)d_in[8];
  const float* Wc_w = (const float*)d_in[9];  const float* Wc_b = (const float*)d_in[10];
  const float* Ws_w = (const float*)d_in[11]; const float* Ws_b = (const float*)d_in[12];
  const float* Ui_w = (const float*)d_in[13]; const float* Ui_b = (const float*)d_in[14];
  const float* Uf_w = (const float*)d_in[15]; const float* Uf_b = (const float*)d_in[16];
  const float* Uo_w = (const float*)d_in[17]; const float* Uo_b = (const float*)d_in[18];
  const float* Uc_w = (const float*)d_in[19]; const float* Uc_b = (const float*)d_in[20];
  const float* Us_w = (const float*)d_in[21]; const float* Us_b = (const float*)d_in[22];
  const float* a1_w = (const float*)d_in[23]; const float* a1_b = (const float*)d_in[24];
  const float* a2_w = (const float*)d_in[25]; const float* a2_b = (const float*)d_in[26];
  const float* r1_w = (const float*)d_in[27]; const float* r1_b = (const float*)d_in[28];
  const float* r2_w = (const float*)d_in[29]; const float* r2_b = (const float*)d_in[30];
  const float* r3_w = (const float*)d_in[31]; const float* r3_b = (const float*)d_in[32];

  char* ws = (char*)d_ws;
  size_t off = 0;
  auto alloc = [&](size_t bytes) -> void* {
    void* p = ws + off;
    off += (bytes + 255) & ~(size_t)255;
    return p;
  };
  bf16* A_big    = (bf16*)alloc((size_t)8192 * 2048 * 2);
  bf16* WG       = (bf16*)alloc((size_t)7168 * 2048 * 2);
  float* bias_bg = (float*)alloc((size_t)7168 * 4);
  bf16* WR2      = (bf16*)alloc((size_t)1024 * 1024 * 2);
  bf16* WR3      = (bf16*)alloc((size_t)1024 * 1024 * 2);
  bf16* G        = (bf16*)alloc((size_t)8192 * 7168 * 2);
  bf16* R2       = (bf16*)alloc((size_t)8192 * 1024 * 2);
  bf16* R3       = (bf16*)alloc((size_t)8192 * 1024 * 2);
  float* alpha   = (float*)alloc((size_t)8192 * 4);

  build_A<<<16384, 256, 0, stream>>>(x, h_prev, A_big);
  build_WG<<<14336, 256, 0, stream>>>(Wi_w, Wf_w, Wo_w, Wc_w, Ws_w,
                                      Ui_w, Uf_w, Uo_w, Uc_w, Us_w, a1_w, r1_w, WG);
  build_bias<<<28, 256, 0, stream>>>(Wi_b, Wf_b, Wo_b, Wc_b, Ws_b,
                                     Ui_b, Uf_b, Uo_b, Uc_b, Us_b, a1_b, r1_b, bias_bg);
  f2b2<<<2048, 256, 0, stream>>>(r2_w, r3_w, WR2, WR3);

  // big fused GEMM: [8192 x 2048] @ [7168 x 2048]^T, 8-wave 256^2 + r1 K-skip
  gemm256<<<896, 512, 0, stream>>>(A_big, 2048, WG, 2048, 2048, bias_bg, G, NBIG, 0, 32);

  // alpha head
  alpha_k<<<2048, 256, 0, stream>>>(G, a2_w, a2_b, alpha);

  // residual chain r2 -> r3 (3-buf 128^2 kernel)
  gemm128<<<512, 256, 0, stream>>>(G + 6144, NBIG, WR2, 1024, 1024, r2_b, R2, 1024, 1, 64);
  gemm128<<<512, 256, 0, stream>>>(R2, 1024, WR3, 1024, 1024, r3_b, R3, 1024, 2, 64);

  final_k<<<4096, 256, 0, stream>>>(G, R3, c_prev, alpha, (float*)d_out);
}

// Round 11
// 399.394 us; speedup vs baseline: 1.1909x; 1.1909x over previous
//
#include <hip/hip_runtime.h>
#include <hip/hip_bf16.h>

typedef __bf16 bf16;
typedef __bf16 bf16x8 __attribute__((ext_vector_type(8)));
typedef __bf16 bf16x4 __attribute__((ext_vector_type(4)));
typedef float f32x4 __attribute__((ext_vector_type(4)));

#define NBIG 7168
#define KBIG 2048

__device__ __forceinline__ float sigmoid_f(float x) { return 1.0f / (1.0f + __expf(-x)); }
__device__ __forceinline__ float tanh_f(float x) { return 1.0f - 2.0f / (__expf(2.0f * x) + 1.0f); }

__device__ __forceinline__ void gload_lds16(const bf16* g, bf16* lds) {
  __builtin_amdgcn_global_load_lds(
      (const __attribute__((address_space(1))) unsigned int*)g,
      (__attribute__((address_space(3))) unsigned int*)lds,
      16, 0, 0);
}

// ---------------- prep kernels ----------------

__global__ __launch_bounds__(256) void build_A(const float* __restrict__ x,
                                               const float* __restrict__ h,
                                               bf16* __restrict__ A) {
  const int i4 = blockIdx.x * 256 + threadIdx.x;
  const int o = i4 * 4;
  const int m = o >> 11;
  const int c = o & 2047;
  const float4 v = (c < 1024) ? *(const float4*)&x[(size_t)m * 1024 + c]
                              : *(const float4*)&h[(size_t)m * 1024 + (c - 1024)];
  bf16x4 b;
  b[0] = (bf16)v.x; b[1] = (bf16)v.y; b[2] = (bf16)v.z; b[3] = (bf16)v.w;
  *(bf16x4*)&A[(size_t)o] = b;
}

__global__ __launch_bounds__(256) void build_WG(
    const float* __restrict__ Wi, const float* __restrict__ Wf, const float* __restrict__ Wo,
    const float* __restrict__ Wc, const float* __restrict__ Ws,
    const float* __restrict__ Ui, const float* __restrict__ Uf, const float* __restrict__ Uo,
    const float* __restrict__ Uc, const float* __restrict__ Us,
    const float* __restrict__ a1w, const float* __restrict__ r1w, bf16* __restrict__ WG) {
  const int i4 = blockIdx.x * 256 + threadIdx.x;
  const int o = i4 * 4;
  const int n = o >> 11;
  const int c = o & 2047;
  const int g = n >> 10;
  const int r = n & 1023;
  float4 v;
  if (g < 5) {
    const float* Wp = g == 0 ? Wi : g == 1 ? Wf : g == 2 ? Wo : g == 3 ? Wc : Ws;
    const float* Up = g == 0 ? Ui : g == 1 ? Uf : g == 2 ? Uo : g == 3 ? Uc : Us;
    v = (c < 1024) ? *(const float4*)&Wp[(size_t)r * 1024 + c]
                   : *(const float4*)&Up[(size_t)r * 1024 + (c - 1024)];
  } else if (g == 5) {
    v = *(const float4*)&a1w[(size_t)r * 2048 + c];
  } else {
    if (c < 1024) return;  // never read: r1 slab K-tiles 0..15 skipped in gemm256
    v = *(const float4*)&r1w[(size_t)r * 1024 + (c - 1024)];
  }
  bf16x4 b;
  b[0] = (bf16)v.x; b[1] = (bf16)v.y; b[2] = (bf16)v.z; b[3] = (bf16)v.w;
  *(bf16x4*)&WG[(size_t)o] = b;
}

__global__ __launch_bounds__(256) void build_bias(
    const float* __restrict__ Wib, const float* __restrict__ Wfb, const float* __restrict__ Wob,
    const float* __restrict__ Wcb, const float* __restrict__ Wsb,
    const float* __restrict__ Uib, const float* __restrict__ Ufb, const float* __restrict__ Uob,
    const float* __restrict__ Ucb, const float* __restrict__ Usb,
    const float* __restrict__ a1b, const float* __restrict__ r1b, float* __restrict__ bias) {
  const int n = blockIdx.x * 256 + threadIdx.x;
  if (n >= NBIG) return;
  const int g = n >> 10, r = n & 1023;
  float v;
  if (g < 5) {
    const float* Wb = g == 0 ? Wib : g == 1 ? Wfb : g == 2 ? Wob : g == 3 ? Wcb : Wsb;
    const float* Ub = g == 0 ? Uib : g == 1 ? Ufb : g == 2 ? Uob : g == 3 ? Ucb : Usb;
    v = Wb[r] + Ub[r];
  } else if (g == 5) v = a1b[r];
  else v = r1b[r];
  bias[n] = v;
}

// both r2_w and r3_w -> bf16 in one launch
__global__ __launch_bounds__(256) void f2b2(const float* __restrict__ s0,
                                            const float* __restrict__ s1,
                                            bf16* __restrict__ d0, bf16* __restrict__ d1) {
  const int i = blockIdx.x * 256 + threadIdx.x;  // < 2*262144
  const int which = i >> 18;
  const int j = i & 262143;
  const float* s = which ? s1 : s0;
  bf16* d = which ? d1 : d0;
  const float4 v = *(const float4*)&s[(size_t)j * 4];
  bf16x4 b;
  b[0] = (bf16)v.x; b[1] = (bf16)v.y; b[2] = (bf16)v.z; b[3] = (bf16)v.w;
  *(bf16x4*)&d[(size_t)j * 4] = b;
}

// ---------------- 256x256 GEMM, BK=64, 16 waves (4x4, 64x64/wave) ----------------
// Best-measured structure this session (r9: 306 us, MfmaUtil 31.6%, 0 conflicts).
// 1024 threads, LDS 128 KiB dbuf, 4 waves/SIMD TLP. Two K-subphases
// {8 ds_read -> 16 MFMA} per tile (no barrier between), then BAR -> STGT (4
// gloads) -> counted VM4 -> BAR. kt0 K-skip for the r1 slab (zero cols never read).
// Swizzle (128-B rows): phys 16B slot = logical ^ (fr&7) on ds_read; inverse
// applied on global staging source (linear gload_lds dest).
// act_mode 0: per-col regions (n>>10: 0,1,2,4=sigmoid, 3=tanh, 5,6=relu); 1: relu; 2: none.

#define BAR __builtin_amdgcn_s_barrier()
#define VM4 asm volatile("s_waitcnt vmcnt(4)" ::: "memory")
#define VM0 asm volatile("s_waitcnt vmcnt(0)" ::: "memory")
#define PRIO1 __builtin_amdgcn_s_setprio(1)
#define PRIO0 __builtin_amdgcn_s_setprio(0)

__global__ __launch_bounds__(1024, 4) void gemm256(
    const bf16* __restrict__ A, int lda,
    const bf16* __restrict__ W, int ldw, int K,
    const float* __restrict__ bias,
    bf16* __restrict__ C, int ldc, int act_mode, int mtiles) {
  __shared__ __align__(16) bf16 sA[2][256 * 64];
  __shared__ __align__(16) bf16 sB[2][256 * 64];

  const int tid = threadIdx.x;
  const int lane = tid & 63;
  const int wv = tid >> 6;   // 0..15
  const int wr = wv >> 2;    // 0..3 -> 64-row quarter
  const int wc = wv & 3;     // 0..3 -> 64-col quarter

  int bmi, bni;
  if (gridDim.x == 896) {
    const int xcd = blockIdx.x & 7;
    const int idx = blockIdx.x >> 3;
    bmi = (xcd >> 2) * 16 + idx / 7;
    bni = (xcd & 3) * 7 + idx % 7;
  } else {
    bmi = blockIdx.x % mtiles;
    bni = blockIdx.x / mtiles;
  }
  const int bm = bmi * 256;
  const int bn = bni * 256;

  // K-skip: r1 slab (bn >= 6144) has zero weights for K < 1024
  const int kt0 = (act_mode == 0 && bni >= 24) ? 16 : 0;

  const int srow = tid >> 3;
  const int scol = ((tid & 7) ^ (srow & 7)) * 8;
  const bf16* pA = A + (size_t)(bm + srow) * lda + scol + (size_t)kt0 * 64;
  const bf16* pB = W + (size_t)(bn + srow) * ldw + scol + (size_t)kt0 * 64;

  const int fr = lane & 15;
  const int lg = lane >> 4;
  const int off0 = (lg * 16) ^ ((fr & 7) << 4);

  const int NT = (K >> 6) - kt0;  // BK=64

  f32x4 acc[4][4] = {};
  bf16x8 ar[4], br[4];

#define STGT(bb, tt)                                                        \
  do {                                                                      \
    const bf16* gA = pA + (size_t)(tt) * 64;                                \
    gload_lds16(gA, &sA[bb][(wv * 8) * 64]);                                \
    gload_lds16(gA + (size_t)128 * lda, &sA[bb][(128 + wv * 8) * 64]);      \
    const bf16* gB = pB + (size_t)(tt) * 64;                                \
    gload_lds16(gB, &sB[bb][(wv * 8) * 64]);                                \
    gload_lds16(gB + (size_t)128 * ldw, &sB[bb][(128 + wv * 8) * 64]);      \
  } while (0)
#define LDF(bb, kkc)                                                             \
  do {                                                                           \
    _Pragma("unroll") for (int mi = 0; mi < 4; ++mi)                             \
        ar[mi] = *(const bf16x8*)((const char*)&sA[bb][0] +                      \
            (wr * 64 + mi * 16 + fr) * 128 + (off0 ^ ((kkc) << 6)));             \
    _Pragma("unroll") for (int nj = 0; nj < 4; ++nj)                             \
        br[nj] = *(const bf16x8*)((const char*)&sB[bb][0] +                      \
            (wc * 64 + nj * 16 + fr) * 128 + (off0 ^ ((kkc) << 6)));             \
  } while (0)
#define MM()                                                                     \
  do {                                                                           \
    _Pragma("unroll") for (int mi = 0; mi < 4; ++mi)                             \
    _Pragma("unroll") for (int nj = 0; nj < 4; ++nj)                             \
      acc[mi][nj] = __builtin_amdgcn_mfma_f32_16x16x32_bf16(                     \
          ar[mi], br[nj], acc[mi][nj], 0, 0, 0);                                 \
  } while (0)

  // prologue: tile0 -> buf0 (completed by VM4), tile1 -> buf1 (4 loads in flight)
  STGT(0, 0);
  STGT(1, 1);
  VM4; BAR;

  for (int t = 0; t + 2 < NT; ++t) {
    const int b = t & 1;
    LDF(b, 0);
    PRIO1; MM(); PRIO0;
    LDF(b, 1);
    PRIO1; MM(); PRIO0;
    BAR;
    STGT(b, t + 2);
    VM4;
    BAR;
  }

  // tail: tile NT-2 (resident), then drain and do tile NT-1
  {
    const int b = NT & 1;
    LDF(b, 0); PRIO1; MM(); PRIO0;
    LDF(b, 1); PRIO1; MM(); PRIO0;
    BAR; VM0; BAR;
    LDF(b ^ 1, 0); PRIO1; MM(); PRIO0;
    LDF(b ^ 1, 1); PRIO1; MM(); PRIO0;
  }

  // C-write: C/D layout col = lane&15, row = (lane>>4)*4 + r
  const int rbase = lg * 4;
#pragma unroll
  for (int j = 0; j < 4; ++j) {
    const int n = bn + wc * 64 + j * 16 + fr;
    const float bv = bias[n];
    const int g = (act_mode == 0) ? (n >> 10) : (act_mode == 1 ? 100 : 101);
#pragma unroll
    for (int mi = 0; mi < 4; ++mi) {
      const size_t mrow = (size_t)(bm + wr * 64 + mi * 16 + rbase);
#pragma unroll
      for (int r = 0; r < 4; ++r) {
        float v = acc[mi][j][r] + bv;
        if (g == 3) v = tanh_f(v);
        else if (g < 5) v = sigmoid_f(v);
        else if (g < 7 || g == 100) v = fmaxf(v, 0.0f);
        C[(mrow + r) * (size_t)ldc + n] = (bf16)v;
      }
    }
  }
#undef STGT
#undef LDF
#undef MM
}

// ---------------- 128x128 GEMM, BK=32, 3-buf, 1 barrier/tile (residual chain) ----
__global__ __launch_bounds__(256, 3) void gemm128(
    const bf16* __restrict__ A, int lda,
    const bf16* __restrict__ W, int ldw, int K,
    const float* __restrict__ bias,
    bf16* __restrict__ C, int ldc, int act_mode, int mtiles) {
  __shared__ __align__(16) bf16 sA[3][128 * 32];
  __shared__ __align__(16) bf16 sB[3][128 * 32];

  const int tid = threadIdx.x;
  const int lane = tid & 63;
  const int wv = tid >> 6;
  const int wr = wv >> 1, wc = wv & 1;

  const int bmi = blockIdx.x % mtiles;
  const int bni = blockIdx.x / mtiles;
  const int bm = bmi * 128;
  const int bn = bni * 128;

  const int srow = tid >> 2;
  const int scol = ((tid & 3) ^ ((tid >> 3) & 3)) * 8;
  const bf16* pA = A + (size_t)(bm + srow) * lda + scol;
  const bf16* pB = W + (size_t)(bn + srow) * ldw + scol;

  const int fr = lane & 15;
  const int lg = lane >> 4;
  const int sw16 = (lg ^ ((fr >> 1) & 3)) << 4;

  const int NT = K >> 5;

  f32x4 acc[4][4] = {};
  bf16x8 ar[4], br[4];

#define STGT(bb, tt)                                                \
  do {                                                              \
    const bf16* gA = pA + (size_t)(tt) * 32;                        \
    bf16* lA = &sA[bb][(wv * 16) * 32];                             \
    gload_lds16(gA, lA);                                            \
    gload_lds16(gA + (size_t)64 * lda, lA + 64 * 32);               \
    const bf16* gB = pB + (size_t)(tt) * 32;                        \
    bf16* lB = &sB[bb][(wv * 16) * 32];                             \
    gload_lds16(gB, lB);                                            \
    gload_lds16(gB + (size_t)64 * ldw, lB + 64 * 32);               \
  } while (0)
#define LDF(bb)                                                                  \
  do {                                                                           \
    _Pragma("unroll") for (int mi = 0; mi < 4; ++mi)                             \
        ar[mi] = *(const bf16x8*)((const char*)&sA[bb][0] +                      \
            (wr * 64 + mi * 16 + fr) * 64 + sw16);                               \
    _Pragma("unroll") for (int nj = 0; nj < 4; ++nj)                             \
        br[nj] = *(const bf16x8*)((const char*)&sB[bb][0] +                      \
            (wc * 64 + nj * 16 + fr) * 64 + sw16);                               \
  } while (0)
#define MM()                                                                     \
  do {                                                                           \
    _Pragma("unroll") for (int mi = 0; mi < 4; ++mi)                             \
    _Pragma("unroll") for (int nj = 0; nj < 4; ++nj)                             \
      acc[mi][nj] = __builtin_amdgcn_mfma_f32_16x16x32_bf16(                     \
          ar[mi], br[nj], acc[mi][nj], 0, 0, 0);                                 \
  } while (0)

  STGT(0, 0);
  STGT(1, 1);
  VM4; BAR;

  int bld = 0, bst = 2;
  for (int t = 0; t + 2 < NT; ++t) {
    STGT(bst, t + 2);
    LDF(bld);
    PRIO1; MM(); PRIO0;
    VM4;
    BAR;
    bld = bld == 2 ? 0 : bld + 1;
    bst = bst == 2 ? 0 : bst + 1;
  }

  LDF(bld);
  PRIO1; MM(); PRIO0;
  VM0; BAR;
  bld = bld == 2 ? 0 : bld + 1;
  LDF(bld);
  PRIO1; MM(); PRIO0;

  const int rbase = lg * 4;
#pragma unroll
  for (int j = 0; j < 4; ++j) {
    const int n = bn + wc * 64 + j * 16 + fr;
    const float bv = bias[n];
    const int g = (act_mode == 0) ? (n >> 10) : (act_mode == 1 ? 100 : 101);
#pragma unroll
    for (int mi = 0; mi < 4; ++mi) {
      const size_t mrow = (size_t)(bm + wr * 64 + mi * 16 + rbase);
#pragma unroll
      for (int r = 0; r < 4; ++r) {
        float v = acc[mi][j][r] + bv;
        if (g == 3) v = tanh_f(v);
        else if (g < 5) v = sigmoid_f(v);
        else if (g < 7 || g == 100) v = fmaxf(v, 0.0f);
        C[(mrow + r) * (size_t)ldc + n] = (bf16)v;
      }
    }
  }
#undef STGT
#undef LDF
#undef MM
}

// ---------------- alpha head ----------------
__global__ __launch_bounds__(256) void alpha_k(const bf16* __restrict__ G,
                                               const float* __restrict__ a2w,
                                               const float* __restrict__ a2b,
                                               float* __restrict__ alpha) {
  const int m = blockIdx.x * 4 + (threadIdx.x >> 6);
  const int lane = threadIdx.x & 63;
  const bf16* row = G + (size_t)m * NBIG + 5120 + lane * 16;
  const bf16x8 v0 = *(const bf16x8*)row;
  const bf16x8 v1 = *(const bf16x8*)(row + 8);
  const float* w = a2w + lane * 16;
  float s = 0.f;
#pragma unroll
  for (int e = 0; e < 8; ++e) s += (float)v0[e] * w[e] + (float)v1[e] * w[8 + e];
#pragma unroll
  for (int off = 32; off > 0; off >>= 1) s += __shfl_down(s, off, 64);
  if (lane == 0) alpha[m] = sigmoid_f(s + a2b[0]);
}

// ---------------- final elementwise ----------------
__global__ __launch_bounds__(256) void final_k(const bf16* __restrict__ G,
                                               const bf16* __restrict__ R3,
                                               const float* __restrict__ c_prev,
                                               const float* __restrict__ alpha,
                                               float* __restrict__ out) {
  const int idx = blockIdx.x * 256 + threadIdx.x;
  const int o = idx * 8;
  const int m = o >> 10;
  const int c = o & 1023;
  const size_t gb = (size_t)m * NBIG;
  const bf16x8 iv = *(const bf16x8*)&G[gb + c];
  const bf16x8 fv = *(const bf16x8*)&G[gb + 1024 + c];
  const bf16x8 ov = *(const bf16x8*)&G[gb + 2048 + c];
  const bf16x8 cv = *(const bf16x8*)&G[gb + 3072 + c];
  const bf16x8 sv = *(const bf16x8*)&G[gb + 4096 + c];
  const bf16x8 rv = *(const bf16x8*)&R3[(size_t)m * 1024 + c];
  const float al = alpha[m];
  const float* cp = &c_prev[(size_t)m * 1024 + c];
  float hbuf[8], cbuf[8];
#pragma unroll
  for (int e = 0; e < 8; ++e) {
    const float ct = (float)fv[e] * cp[e] + (float)iv[e] * (float)cv[e] * (float)sv[e] * al
                     + (float)rv[e];
    cbuf[e] = ct;
    hbuf[e] = (float)ov[e] * tanh_f(ct);
  }
  float* oh = out + (size_t)m * 1024 + c;
  float* oc = out + (size_t)8192 * 1024 + (size_t)m * 1024 + c;
#pragma unroll
  for (int e = 0; e < 8; ++e) { oh[e] = hbuf[e]; oc[e] = cbuf[e]; }
}

// ---------------- launch ----------------
extern "C" void kernel_launch(void* const* d_in, const int* in_sizes, int n_in,
                              void* d_out, int out_size, void* d_ws, size_t ws_size,
                              hipStream_t stream) {
  const float* x      = (const float*)d_in[0];
  const float* h_prev = (const float*)d_in[1];
  const float* c_prev = (const float*)d_in[2];
  const float* Wi_w = (const float*)d_in[3];  const float* Wi_b = (const float*)d_in[4];
  const float* Wf_w = (const float*)d_in[5];  const float* Wf_b = (const float*)d_in[6];
  const float* Wo_w = (const float*)d_in[7];  const float* Wo_b = (const float*)d_in[8];
  const float* Wc_w = (const float*)d_in[9];  const float* Wc_b = (const float*)d_in[10];
  const float* Ws_w = (const float*)d_in[11]; const float* Ws_b = (const float*)d_in[12];
  const float* Ui_w = (const float*)d_in[13]; const float* Ui_b = (const float*)d_in[14];
  const float* Uf_w = (const float*)d_in[15]; const float* Uf_b = (const float*)d_in[16];
  const float* Uo_w = (const float*)d_in[17]; const float* Uo_b = (const float*)d_in[18];
  const float* Uc_w = (const float*)d_in[19]; const float* Uc_b = (const float*)d_in[20];
  const float* Us_w = (const float*)d_in[21]; const float* Us_b = (const float*)d_in[22];
  const float* a1_w = (const float*)d_in[23]; const float* a1_b = (const float*)d_in[24];
  const float* a2_w = (const float*)d_in[25]; const float* a2_b = (const float*)d_in[26];
  const float* r1_w = (const float*)d_in[27]; const float* r1_b = (const float*)d_in[28];
  const float* r2_w = (const float*)d_in[29]; const float* r2_b = (const float*)d_in[30];
  const float* r3_w = (const float*)d_in[31]; const float* r3_b = (const float*)d_in[32];

  char* ws = (char*)d_ws;
  size_t off = 0;
  auto alloc = [&](size_t bytes) -> void* {
    void* p = ws + off;
    off += (bytes + 255) & ~(size_t)255;
    return p;
  };
  bf16* A_big    = (bf16*)alloc((size_t)8192 * 2048 * 2);
  bf16* WG       = (bf16*)alloc((size_t)7168 * 2048 * 2);
  float* bias_bg = (float*)alloc((size_t)7168 * 4);
  bf16* WR2      = (bf16*)alloc((size_t)1024 * 1024 * 2);
  bf16* WR3      = (bf16*)alloc((size_t)1024 * 1024 * 2);
  bf16* G        = (bf16*)alloc((size_t)8192 * 7168 * 2);
  bf16* R2       = (bf16*)alloc((size_t)8192 * 1024 * 2);
  bf16* R3       = (bf16*)alloc((size_t)8192 * 1024 * 2);
  float* alpha   = (float*)alloc((size_t)8192 * 4);

  build_A<<<16384, 256, 0, stream>>>(x, h_prev, A_big);
  build_WG<<<14336, 256, 0, stream>>>(Wi_w, Wf_w, Wo_w, Wc_w, Ws_w,
                                      Ui_w, Uf_w, Uo_w, Uc_w, Us_w, a1_w, r1_w, WG);
  build_bias<<<28, 256, 0, stream>>>(Wi_b, Wf_b, Wo_b, Wc_b, Ws_b,
                                     Ui_b, Uf_b, Uo_b, Uc_b, Us_b, a1_b, r1_b, bias_bg);
  f2b2<<<2048, 256, 0, stream>>>(r2_w, r3_w, WR2, WR3);

  // big fused GEMM: [8192 x 2048] @ [7168 x 2048]^T, 16-wave 256^2 + r1 K-skip
  gemm256<<<896, 1024, 0, stream>>>(A_big, 2048, WG, 2048, 2048, bias_bg, G, NBIG, 0, 32);

  // alpha head
  alpha_k<<<2048, 256, 0, stream>>>(G, a2_w, a2_b, alpha);

  // residual chain r2 -> r3 (3-buf 128^2 kernel)
  gemm128<<<512, 256, 0, stream>>>(G + 6144, NBIG, WR2, 1024, 1024, r2_b, R2, 1024, 1, 64);
  gemm128<<<512, 256, 0, stream>>>(R2, 1024, WR3, 1024, 1024, r3_b, R3, 1024, 2, 64);

  final_k<<<4096, 256, 0, stream>>>(G, R3, c_prev, alpha, (float*)d_out);
}